// Round 2
// baseline (819.099 us; speedup 1.0000x reference)
//
#include <hip/hip_runtime.h>

typedef unsigned short u16;
typedef __attribute__((ext_vector_type(8))) _Float16 f16x8;
typedef __attribute__((ext_vector_type(4))) float f32x4;

#define S_CTX 2048
#define DMODEL 2048

__device__ __forceinline__ u16 f2h(float f) {
  _Float16 h = (_Float16)f; u16 u; __builtin_memcpy(&u, &h, 2); return u;
}
__device__ __forceinline__ float h2f(u16 u) {
  _Float16 h; __builtin_memcpy(&h, &u, 2); return (float)h;
}
__device__ __forceinline__ void gload16(const u16* g, u16* l) {
  __builtin_amdgcn_global_load_lds(
      (const __attribute__((address_space(1))) unsigned int*)g,
      (__attribute__((address_space(3))) unsigned int*)l, 16, 0, 0);
}

// One fused split pass. x -> fp16 pair (no scale). Wq,Wk -> fp16 pair (x64).
// Wv,Wo -> fp16 single (x64). Scales folded out downstream (q-prescale, /4096).
__global__ void split_all(const float* __restrict__ x, const float* __restrict__ Wq,
                          const float* __restrict__ Wk, const float* __restrict__ Wv,
                          const float* __restrict__ Wo,
                          u16* xh, u16* xl, u16* Wqh, u16* Wql,
                          u16* Wkh, u16* Wkl, u16* Wvh, u16* Woh) {
  size_t i = (size_t)blockIdx.x * 256 + threadIdx.x;
  const size_t NX = 8388608, NW = 4194304;
  if (i < NX) {
    float v = x[i];
    u16 h = f2h(v);
    xh[i] = h; xl[i] = f2h(v - h2f(h));
  } else {
    size_t j = i - NX;
    int wsel = (int)(j >> 22);
    size_t o = j & (NW - 1);
    if (wsel == 0) { float v = Wq[o] * 64.f; u16 h = f2h(v); Wqh[o] = h; Wql[o] = f2h(v - h2f(h)); }
    else if (wsel == 1) { float v = Wk[o] * 64.f; u16 h = f2h(v); Wkh[o] = h; Wkl[o] = f2h(v - h2f(h)); }
    else if (wsel == 2) { Wvh[o] = f2h(Wv[o] * 64.f); }
    else { Woh[o] = f2h(Wo[o] * 64.f); }
  }
}

// ---------------------------------------------------------------------------
// C[M,N] = A * B^T, fp16 MFMA, 128x128 tile, 256 thr = 4 waves (2M x 2N),
// BK=32, round-0 2-barrier loop structure (known-good, 876 TF).
//
// LDS layout (NEW, round-1-verified conflict-free): per matrix 8 chunks of
// 1 KiB; chunk c = rh*4 + q holds rows rh*64+[0,64) at k-quad q ([8 u16]).
// global_load_lds writes linearly (wave-uniform base c*512 + lane*8 u16);
// the SOURCE address is permuted to match (lane -> row rh*64+lane, col q*8).
// Fragment ds_read_b128: 16 consecutive lanes read 16 consecutive rows
// = 256B contiguous -> 0 bank conflicts (round-1 measured: 2.1e7 -> 0).
//
// NT==3: AhBh+AhBl+AlBh   NT==1: AhBh
// MODE 0: f32*oscale -> Cf
// MODE 2: V^T fp16 -> Ch  ([b][h][d][s])
// MODE 3: fused RoPE -> fp16 single Ch (tile = one full head; d<->d+64
//         exchanged through LDS per i-block; oscale folds the q prescale).
// ---------------------------------------------------------------------------
template <int NT, int MODE>
__device__ __forceinline__ void gemm_core(
    u16* sm, const u16* __restrict__ Am, const u16* __restrict__ Alm,
    const u16* __restrict__ Bm, const u16* __restrict__ Blm,
    float* __restrict__ Cf, u16* __restrict__ Ch,
    const float* __restrict__ cosT, const float* __restrict__ sinT,
    int N, int K, int m0, int n0, float oscale) {
  const int tid = threadIdx.x;
  const int w = tid >> 6, lane = tid & 63;
  const int quad = lane >> 4, l16 = lane & 15;
  const int wm = (w >> 1) << 6, wn = (w & 1) << 6;

  // fragment read bases (u16 units): chunk (rh, quad) at rh*2048 + quad*512
  const int abase = ((w >> 1) << 11) + (quad << 9) + (l16 << 3);
  const int bbase = 4096 + ((w & 1) << 11) + (quad << 9) + (l16 << 3);

  f32x4 acc[4][4];
#pragma unroll
  for (int i = 0; i < 4; ++i)
#pragma unroll
    for (int n = 0; n < 4; ++n) acc[i][n] = (f32x4){0.f, 0.f, 0.f, 0.f};

  for (int k0 = 0; k0 < K; k0 += 32) {
    __syncthreads();
#pragma unroll
    for (int j = 0; j < 2; ++j) {
      const int c = (w << 1) + j;     // chunk id 0..7 (wave-uniform)
      const int q = c & 3, rh = c >> 2;
      const int ldst = c << 9;        // c * 512 u16
      size_t ga = (size_t)(m0 + rh * 64 + lane) * K + k0 + q * 8;
      size_t gb = (size_t)(n0 + rh * 64 + lane) * K + k0 + q * 8;
      gload16(Am + ga, &sm[ldst]);
      gload16(Bm + gb, &sm[4096 + ldst]);
      if (NT == 3) {
        gload16(Blm + gb, &sm[8192 + ldst]);
        gload16(Alm + ga, &sm[12288 + ldst]);
      }
    }
    __syncthreads();
    f16x8 ah[4], al[4], bh[4], bl[4];
#pragma unroll
    for (int i = 0; i < 4; ++i) {
      ah[i] = *(const f16x8*)&sm[abase + i * 128];
      if (NT == 3) al[i] = *(const f16x8*)&sm[12288 + abase + i * 128];
    }
#pragma unroll
    for (int n = 0; n < 4; ++n) {
      bh[n] = *(const f16x8*)&sm[bbase + n * 128];
      if (NT == 3) bl[n] = *(const f16x8*)&sm[4096 + bbase + n * 128];
    }
#pragma unroll
    for (int i = 0; i < 4; ++i)
#pragma unroll
      for (int n = 0; n < 4; ++n) {
        acc[i][n] = __builtin_amdgcn_mfma_f32_16x16x32_f16(ah[i], bh[n], acc[i][n], 0, 0, 0);
        if (NT == 3) {
          acc[i][n] = __builtin_amdgcn_mfma_f32_16x16x32_f16(ah[i], bl[n], acc[i][n], 0, 0, 0);
          acc[i][n] = __builtin_amdgcn_mfma_f32_16x16x32_f16(al[i], bh[n], acc[i][n], 0, 0, 0);
        }
      }
  }

  // epilogue: C/D layout row=(lane>>4)*4+r, col=lane&15
  if (MODE == 3) {
    // fused RoPE: tile cols n0..n0+127 are exactly one head (d = local col).
    float* fs = (float*)sm;  // 2 pairs x 16 rows x 128 cols f32 = 16 KiB
    const int p = w >> 1;
#pragma unroll
    for (int i = 0; i < 4; ++i) {
      __syncthreads();  // prev i-block reads (or K-loop LDS reads) done
#pragma unroll
      for (int n = 0; n < 4; ++n)
#pragma unroll
        for (int r = 0; r < 4; ++r)
          fs[p * 2048 + (quad * 4 + r) * 128 + wn + n * 16 + l16] = acc[i][n][r];
      __syncthreads();
#pragma unroll
      for (int n = 0; n < 4; ++n) {
        const int col = wn + n * 16 + l16;
        const int cc = col ^ 64;
        const float sgn = (col < 64) ? -1.f : 1.f;
#pragma unroll
        for (int r = 0; r < 4; ++r) {
          const int row16 = quad * 4 + r;
          const int grow = m0 + wm + i * 16 + row16;
          const int s = grow & (S_CTX - 1);
          const float c = cosT[s * 128 + col];
          const float sn = sinT[s * 128 + col];
          const float x = fs[p * 2048 + row16 * 128 + col];
          const float xp = fs[p * 2048 + row16 * 128 + cc];
          Ch[(size_t)grow * N + n0 + col] = f2h((x * c + sgn * xp * sn) * oscale);
        }
      }
    }
    return;
  }
#pragma unroll
  for (int i = 0; i < 4; ++i)
#pragma unroll
    for (int n = 0; n < 4; ++n) {
      const int row0 = m0 + wm + i * 16 + quad * 4;
      const int col = n0 + wn + n * 16 + l16;
      if (MODE == 0) {
#pragma unroll
        for (int r = 0; r < 4; ++r) Cf[(size_t)(row0 + r) * N + col] = acc[i][n][r] * oscale;
      } else {
        int brow = row0 >> 11, s0 = row0 & 2047;
        int hh = col >> 7, d = col & 127;
        ushort4 pk;
        pk.x = f2h(acc[i][n][0]);
        pk.y = f2h(acc[i][n][1]);
        pk.z = f2h(acc[i][n][2]);
        pk.w = f2h(acc[i][n][3]);
        *(ushort4*)(Ch + ((size_t)(brow * 16 + hh) * 128 + d) * 2048 + s0) = pk;
      }
    }
}

// Fused QKV projection + RoPE: grid (16, 32, 3).
// z=0: Q (3-term, rope + qs prescale); z=1: K (3-term, rope); z=2: V (1-term, V^T out)
__global__ __launch_bounds__(256) void qkv_kernel(
    const u16* __restrict__ xh, const u16* __restrict__ xl,
    const u16* __restrict__ Wqh, const u16* __restrict__ Wql,
    const u16* __restrict__ Wkh, const u16* __restrict__ Wkl,
    const u16* __restrict__ Wvh,
    const float* __restrict__ cosT, const float* __restrict__ sinT,
    u16* qh, u16* kh, u16* vt) {
  __shared__ u16 sm[4 * 4096];
  const int m0 = blockIdx.y << 7, n0 = blockIdx.x << 7;
  const float qs = 0.002762135864009951f;  // sqrt(128)/4096
  if (blockIdx.z == 0)
    gemm_core<3, 3>(sm, xh, xl, Wqh, Wql, nullptr, qh, cosT, sinT, DMODEL, DMODEL, m0, n0, qs);
  else if (blockIdx.z == 1)
    gemm_core<3, 3>(sm, xh, xl, Wkh, Wkl, nullptr, kh, cosT, sinT, DMODEL, DMODEL, m0, n0, 1.f);
  else
    gemm_core<1, 2>(sm, xh, nullptr, Wvh, nullptr, nullptr, vt, nullptr, nullptr, DMODEL, DMODEL, m0, n0, 1.f);
}

// out = (ch * Woh^T) / 4096  (1-term fp16; dropped terms ~1.5e-4)
__global__ __launch_bounds__(256) void out_kernel(
    const u16* __restrict__ ch, const u16* __restrict__ Woh, float* __restrict__ out) {
  __shared__ u16 sm[2 * 4096];
  gemm_core<1, 0>(sm, ch, nullptr, Woh, nullptr, out, nullptr, nullptr, nullptr, DMODEL, DMODEL,
                  blockIdx.y << 7, blockIdx.x << 7, 1.f / 4096.f);
}

// Flash attention, causal. 1-term fp16 QK (q pre-scaled), f32 online softmax,
// fp16 P and PV with V^T [b][h][d][s]. BQ=128: 512 thr = 8 waves x 16 q-rows
// sharing K/V tiles (BK=64). P in its OWN per-wave LDS buffer (no aliasing,
// no barrier needed for it: strictly within-wave write->read). 2 barriers/iter.
// Register prefetch of tile kt+1; qt descending; ch = 64*ctx fp16.
__global__ __launch_bounds__(512) void attn_kernel(
    const u16* __restrict__ Qh, const u16* __restrict__ Kh,
    const u16* __restrict__ VT, u16* __restrict__ Ch) {
  const int qt = gridDim.x - 1 - blockIdx.x;  // big blocks first
  const int bh = blockIdx.y;
  const int b = bh >> 4, h = bh & 15;
  const int tid = threadIdx.x;
  const int w = tid >> 6, lane = tid & 63;
  const int quad = lane >> 4, l16 = lane & 15;

  __shared__ u16 sKh[64 * 136];   // K-tile [k][d] pitch 136
  __shared__ u16 sVt[128 * 72];   // V^T tile [d][k], pitch 72
  __shared__ u16 sPb[8 * 1088];   // per-wave P, 16 x 68 each (dedicated)
  u16* sP = &sPb[w * 1088];

  const size_t bhbase = (size_t)b * S_CTX * DMODEL + (size_t)h * 128;
  const size_t vtbase = (size_t)bh * 128 * 2048;

  int kr[2], kc[2], vr[2], vc[2];
#pragma unroll
  for (int j = 0; j < 2; ++j) {
    int c = j * 512 + tid;
    kr[j] = c >> 4; kc[j] = (c & 15) << 3;
    vr[j] = c >> 3; vc[j] = (c & 7) << 3;
  }

  // Q fragments; wave w owns q-rows qt*128 + w*16 + [0,16)
  const int qr0 = qt * 128 + w * 16;
  const size_t qoff = bhbase + (size_t)(qr0 + l16) * DMODEL;
  f16x8 qf[4];
#pragma unroll
  for (int c = 0; c < 4; ++c) qf[c] = *(const f16x8*)(Qh + qoff + c * 32 + quad * 8);

  f32x4 oacc[8];
#pragma unroll
  for (int d = 0; d < 8; ++d) oacc[d] = (f32x4){0.f, 0.f, 0.f, 0.f};
  float m_r[4] = {-INFINITY, -INFINITY, -INFINITY, -INFINITY};
  float l_r[4] = {0.f, 0.f, 0.f, 0.f};

  f16x8 rkh[2], rvt[2];
#pragma unroll
  for (int j = 0; j < 2; ++j) {
    rkh[j] = *(const f16x8*)(Kh + bhbase + (size_t)kr[j] * DMODEL + kc[j]);
    rvt[j] = *(const f16x8*)(VT + vtbase + (size_t)vr[j] * 2048 + vc[j]);
  }

  const int nkt = 2 * qt + 2;
  for (int kt = 0; kt < nkt; ++kt) {
    __syncthreads();  // (1) prev iter QK/PV reads of sKh/sVt done
#pragma unroll
    for (int j = 0; j < 2; ++j) {
      *(f16x8*)&sKh[kr[j] * 136 + kc[j]] = rkh[j];
      *(f16x8*)&sVt[vr[j] * 72 + vc[j]] = rvt[j];
    }
    __syncthreads();  // (2) tiles visible
    if (kt + 1 < nkt) {
#pragma unroll
      for (int j = 0; j < 2; ++j) {
        size_t g = bhbase + (size_t)((kt + 1) * 64 + kr[j]) * DMODEL + kc[j];
        rkh[j] = *(const f16x8*)(Kh + g);
        rvt[j] = *(const f16x8*)(VT + vtbase + (size_t)vr[j] * 2048 + (kt + 1) * 64 + vc[j]);
      }
    }

    const bool active = (kt * 64) <= (qr0 + 15);
    if (active) {
      f32x4 sacc[4];
#pragma unroll
      for (int n = 0; n < 4; ++n) sacc[n] = (f32x4){0.f, 0.f, 0.f, 0.f};
#pragma unroll
      for (int n = 0; n < 4; ++n)
#pragma unroll
        for (int c = 0; c < 4; ++c) {
          f16x8 kf = *(const f16x8*)&sKh[(n * 16 + l16) * 136 + c * 32 + quad * 8];
          sacc[n] = __builtin_amdgcn_mfma_f32_16x16x32_f16(qf[c], kf, sacc[n], 0, 0, 0);
        }

      float pm[4][4];
      float rowmax[4] = {-INFINITY, -INFINITY, -INFINITY, -INFINITY};
#pragma unroll
      for (int n = 0; n < 4; ++n)
#pragma unroll
        for (int r = 0; r < 4; ++r) {
          float sc = sacc[n][r];
          int qi = qr0 + quad * 4 + r;
          int ki = kt * 64 + n * 16 + l16;
          if (ki > qi) sc = -INFINITY;
          pm[n][r] = sc;
          rowmax[r] = fmaxf(rowmax[r], sc);
        }
#pragma unroll
      for (int off = 1; off < 16; off <<= 1)
#pragma unroll
        for (int r = 0; r < 4; ++r)
          rowmax[r] = fmaxf(rowmax[r], __shfl_xor(rowmax[r], off, 64));

      float alphav[4];
#pragma unroll
      for (int r = 0; r < 4; ++r) {
        float mnew = fmaxf(m_r[r], rowmax[r]);
        alphav[r] = __expf(m_r[r] - mnew);
        m_r[r] = mnew;
        l_r[r] *= alphav[r];
      }
      float rowsum[4] = {0.f, 0.f, 0.f, 0.f};
#pragma unroll
      for (int n = 0; n < 4; ++n)
#pragma unroll
        for (int r = 0; r < 4; ++r) {
          float p = __expf(pm[n][r] - m_r[r]);
          pm[n][r] = p;
          rowsum[r] += p;
        }
#pragma unroll
      for (int off = 1; off < 16; off <<= 1)
#pragma unroll
        for (int r = 0; r < 4; ++r) rowsum[r] += __shfl_xor(rowsum[r], off, 64);
#pragma unroll
      for (int r = 0; r < 4; ++r) l_r[r] += rowsum[r];

#pragma unroll
      for (int d = 0; d < 8; ++d)
#pragma unroll
        for (int r = 0; r < 4; ++r) oacc[d][r] *= alphav[r];

      // P (C-layout) -> per-wave dedicated LDS region -> A-layout
#pragma unroll
      for (int n = 0; n < 4; ++n)
#pragma unroll
        for (int r = 0; r < 4; ++r)
          sP[(quad * 4 + r) * 68 + n * 16 + l16] = f2h(pm[n][r]);

      // O += P.V
#pragma unroll
      for (int c = 0; c < 2; ++c) {
        f16x8 pf = *(const f16x8*)&sP[l16 * 68 + c * 32 + quad * 8];
#pragma unroll
        for (int d = 0; d < 8; ++d) {
          f16x8 vf = *(const f16x8*)&sVt[(d * 16 + l16) * 72 + c * 32 + quad * 8];
          oacc[d] = __builtin_amdgcn_mfma_f32_16x16x32_f16(pf, vf, oacc[d], 0, 0, 0);
        }
      }
    }
  }

  float invl[4];
#pragma unroll
  for (int r = 0; r < 4; ++r) invl[r] = 1.f / l_r[r];
#pragma unroll
  for (int d = 0; d < 8; ++d)
#pragma unroll
    for (int r = 0; r < 4; ++r) {
      int row = qr0 + quad * 4 + r;
      Ch[bhbase + (size_t)row * DMODEL + d * 16 + l16] = f2h(oacc[d][r] * invl[r]);
    }
}

extern "C" void kernel_launch(void* const* d_in, const int* in_sizes, int n_in,
                              void* d_out, int out_size, void* d_ws, size_t ws_size,
                              hipStream_t stream) {
  const float* x    = (const float*)d_in[0];
  const float* Wq   = (const float*)d_in[1];
  const float* Wk   = (const float*)d_in[2];
  const float* Wv   = (const float*)d_in[3];
  const float* Wo   = (const float*)d_in[4];
  const float* cosT = (const float*)d_in[5];
  const float* sinT = (const float*)d_in[6];
  float* out = (float*)d_out;

  const size_t NX = 8388608;   // 2*2048*2048
  const size_t NW = 4194304;   // 2048*2048
  u16* p = (u16*)d_ws;
  u16* xh  = p; p += NX;  u16* xl  = p; p += NX;
  u16* Wqh = p; p += NW;  u16* Wql = p; p += NW;
  u16* Wkh = p; p += NW;  u16* Wkl = p; p += NW;
  u16* Wvh = p; p += NW;  u16* Woh = p; p += NW;
  u16* qh  = p; p += NX;  u16* kh  = p; p += NX;
  u16* vt  = p; p += NX;
  u16* ch  = p; p += NX;
  // ~150 MiB of d_ws

  split_all<<<98304, 256, 0, stream>>>(x, Wq, Wk, Wv, Wo,
                                       xh, xl, Wqh, Wql, Wkh, Wkl, Wvh, Woh);

  qkv_kernel<<<dim3(16, 32, 3), 256, 0, stream>>>(xh, xl, Wqh, Wql, Wkh, Wkl, Wvh,
                                                  cosT, sinT, qh, kh, vt);

  attn_kernel<<<dim3(16, 32), 512, 0, stream>>>(qh, kh, vt, ch);

  out_kernel<<<dim3(16, 32), 256, 0, stream>>>(ch, Woh, out);
}

// Round 3
// 647.094 us; speedup vs baseline: 1.2658x; 1.2658x over previous
//
#include <hip/hip_runtime.h>

typedef unsigned short u16;
typedef __attribute__((ext_vector_type(8))) _Float16 f16x8;
typedef __attribute__((ext_vector_type(4))) float f32x4;

#define S_CTX 2048
#define DMODEL 2048

__device__ __forceinline__ u16 f2h(float f) {
  _Float16 h = (_Float16)f; u16 u; __builtin_memcpy(&u, &h, 2); return u;
}
__device__ __forceinline__ float h2f(u16 u) {
  _Float16 h; __builtin_memcpy(&h, &u, 2); return (float)h;
}
__device__ __forceinline__ void gload16(const u16* g, u16* l) {
  __builtin_amdgcn_global_load_lds(
      (const __attribute__((address_space(1))) unsigned int*)g,
      (__attribute__((address_space(3))) unsigned int*)l, 16, 0, 0);
}

// One fused split pass. x -> fp16 pair (no scale). Wq,Wk -> fp16 pair (x64).
// Wv,Wo -> fp16 single (x64). Scales folded out downstream (q-prescale, /4096).
__global__ void split_all(const float* __restrict__ x, const float* __restrict__ Wq,
                          const float* __restrict__ Wk, const float* __restrict__ Wv,
                          const float* __restrict__ Wo,
                          u16* xh, u16* xl, u16* Wqh, u16* Wql,
                          u16* Wkh, u16* Wkl, u16* Wvh, u16* Woh) {
  size_t i = (size_t)blockIdx.x * 256 + threadIdx.x;
  const size_t NX = 8388608, NW = 4194304;
  if (i < NX) {
    float v = x[i];
    u16 h = f2h(v);
    xh[i] = h; xl[i] = f2h(v - h2f(h));
  } else {
    size_t j = i - NX;
    int wsel = (int)(j >> 22);
    size_t o = j & (NW - 1);
    if (wsel == 0) { float v = Wq[o] * 64.f; u16 h = f2h(v); Wqh[o] = h; Wql[o] = f2h(v - h2f(h)); }
    else if (wsel == 1) { float v = Wk[o] * 64.f; u16 h = f2h(v); Wkh[o] = h; Wkl[o] = f2h(v - h2f(h)); }
    else if (wsel == 2) { Wvh[o] = f2h(Wv[o] * 64.f); }
    else { Woh[o] = f2h(Wo[o] * 64.f); }
  }
}

// ---------------------------------------------------------------------------
// C[M,N] = A * B^T, fp16 MFMA, 128x128 tile, 256 thr = 4 waves (2M x 2N),
// BK=32, round-0 2-barrier loop + round-0 COALESCED staging (16x64B rows per
// wave-instr), plus an XOR chunk swizzle that is coalescing-neutral:
//
//   store: lane (row=lane>>2, c=lane&3) fetches global chunk c ^ ((row>>1)&3)
//          (the 4 lanes of a row still cover the same 64B segment, permuted)
//   read:  fragment chunk addr = quad ^ ((l16>>1)&3)
//
// Bank math: ds_read_b128, 16 lanes at 64B row stride. Unswizzled granule
// (4*row + quad) mod 8 -> 8-way conflict (round-0's 2.1e7). Swizzled:
// (4*l16 + quad^((l16>>1)&3)) mod 8 covers all 8 granule groups exactly
// twice -> 2-way = free (m136). Data delivered to MFMA is bit-identical.
//
// NT==3: AhBh+AhBl+AlBh   NT==1: AhBh
// MODE 0: f32*oscale -> Cf
// MODE 2: V^T fp16 -> Ch  ([b][h][d][s])
// MODE 3: fused RoPE -> fp16 single Ch (tile = one full head; d<->d+64
//         exchanged through LDS per i-block; oscale folds the q prescale).
// ---------------------------------------------------------------------------
template <int NT, int MODE>
__device__ __forceinline__ void gemm_core(
    u16* sm, const u16* __restrict__ Am, const u16* __restrict__ Alm,
    const u16* __restrict__ Bm, const u16* __restrict__ Blm,
    float* __restrict__ Cf, u16* __restrict__ Ch,
    const float* __restrict__ cosT, const float* __restrict__ sinT,
    int N, int K, int m0, int n0, float oscale) {
  const int tid = threadIdx.x;
  const int w = tid >> 6, lane = tid & 63;
  const int quad = lane >> 4, l16 = lane & 15;
  const int wm = (w >> 1) << 6, wn = (w & 1) << 6;
  const int lrow = lane >> 2, lcol = (lane & 3) << 3;
  // source-side swizzle (u16 units): chunk ^= (row>>1)&3
  const int lcs = lcol ^ (((lrow >> 1) & 3) << 3);
  // read-side swizzle: same involution
  const int qsw = (quad << 3) ^ (((l16 >> 1) & 3) << 3);

  f32x4 acc[4][4];
#pragma unroll
  for (int i = 0; i < 4; ++i)
#pragma unroll
    for (int n = 0; n < 4; ++n) acc[i][n] = (f32x4){0.f, 0.f, 0.f, 0.f};

  for (int k0 = 0; k0 < K; k0 += 32) {
    __syncthreads();
#pragma unroll
    for (int j = 0; j < 2; ++j) {
      int r = w * 32 + j * 16 + lrow;
      int lb = (w * 32 + j * 16) * 32;  // wave-uniform LDS base (u16)
      size_t ga = (size_t)(m0 + r) * K + k0 + lcs;
      size_t gb = (size_t)(n0 + r) * K + k0 + lcs;
      gload16(Am + ga, &sm[lb]);
      gload16(Bm + gb, &sm[4096 + lb]);
      if (NT == 3) {
        gload16(Blm + gb, &sm[8192 + lb]);
        gload16(Alm + ga, &sm[12288 + lb]);
      }
    }
    __syncthreads();
    f16x8 ah[4], al[4], bh[4], bl[4];
#pragma unroll
    for (int i = 0; i < 4; ++i) {
      int o = (wm + i * 16 + l16) * 32 + qsw;
      ah[i] = *(const f16x8*)&sm[o];
      if (NT == 3) al[i] = *(const f16x8*)&sm[12288 + o];
    }
#pragma unroll
    for (int n = 0; n < 4; ++n) {
      int o = (wn + n * 16 + l16) * 32 + qsw;
      bh[n] = *(const f16x8*)&sm[4096 + o];
      if (NT == 3) bl[n] = *(const f16x8*)&sm[8192 + o];
    }
#pragma unroll
    for (int i = 0; i < 4; ++i)
#pragma unroll
      for (int n = 0; n < 4; ++n) {
        acc[i][n] = __builtin_amdgcn_mfma_f32_16x16x32_f16(ah[i], bh[n], acc[i][n], 0, 0, 0);
        if (NT == 3) {
          acc[i][n] = __builtin_amdgcn_mfma_f32_16x16x32_f16(ah[i], bl[n], acc[i][n], 0, 0, 0);
          acc[i][n] = __builtin_amdgcn_mfma_f32_16x16x32_f16(al[i], bh[n], acc[i][n], 0, 0, 0);
        }
      }
  }

  // epilogue: C/D layout row=(lane>>4)*4+r, col=lane&15
  if (MODE == 3) {
    // fused RoPE: tile cols n0..n0+127 are exactly one head (d = local col).
    float* fs = (float*)sm;  // 2 pairs x 16 rows x 128 cols f32 = 16 KiB
    const int p = w >> 1;
#pragma unroll
    for (int i = 0; i < 4; ++i) {
      __syncthreads();  // prev i-block reads (or K-loop LDS reads) done
#pragma unroll
      for (int n = 0; n < 4; ++n)
#pragma unroll
        for (int r = 0; r < 4; ++r)
          fs[p * 2048 + (quad * 4 + r) * 128 + wn + n * 16 + l16] = acc[i][n][r];
      __syncthreads();
#pragma unroll
      for (int n = 0; n < 4; ++n) {
        const int col = wn + n * 16 + l16;
        const int cc = col ^ 64;
        const float sgn = (col < 64) ? -1.f : 1.f;
#pragma unroll
        for (int r = 0; r < 4; ++r) {
          const int row16 = quad * 4 + r;
          const int grow = m0 + wm + i * 16 + row16;
          const int s = grow & (S_CTX - 1);
          const float c = cosT[s * 128 + col];
          const float sn = sinT[s * 128 + col];
          const float x = fs[p * 2048 + row16 * 128 + col];
          const float xp = fs[p * 2048 + row16 * 128 + cc];
          Ch[(size_t)grow * N + n0 + col] = f2h((x * c + sgn * xp * sn) * oscale);
        }
      }
    }
    return;
  }
#pragma unroll
  for (int i = 0; i < 4; ++i)
#pragma unroll
    for (int n = 0; n < 4; ++n) {
      const int row0 = m0 + wm + i * 16 + quad * 4;
      const int col = n0 + wn + n * 16 + l16;
      if (MODE == 0) {
#pragma unroll
        for (int r = 0; r < 4; ++r) Cf[(size_t)(row0 + r) * N + col] = acc[i][n][r] * oscale;
      } else {
        int brow = row0 >> 11, s0 = row0 & 2047;
        int hh = col >> 7, d = col & 127;
        ushort4 pk;
        pk.x = f2h(acc[i][n][0]);
        pk.y = f2h(acc[i][n][1]);
        pk.z = f2h(acc[i][n][2]);
        pk.w = f2h(acc[i][n][3]);
        *(ushort4*)(Ch + ((size_t)(brow * 16 + hh) * 128 + d) * 2048 + s0) = pk;
      }
    }
}

// Fused QKV projection + RoPE: grid (16, 32, 3).
// z=0: Q (3-term, rope + qs prescale); z=1: K (3-term, rope); z=2: V (1-term, V^T out)
__global__ __launch_bounds__(256) void qkv_kernel(
    const u16* __restrict__ xh, const u16* __restrict__ xl,
    const u16* __restrict__ Wqh, const u16* __restrict__ Wql,
    const u16* __restrict__ Wkh, const u16* __restrict__ Wkl,
    const u16* __restrict__ Wvh,
    const float* __restrict__ cosT, const float* __restrict__ sinT,
    u16* qh, u16* kh, u16* vt) {
  __shared__ u16 sm[4 * 4096];
  const int m0 = blockIdx.y << 7, n0 = blockIdx.x << 7;
  const float qs = 0.002762135864009951f;  // sqrt(128)/4096
  if (blockIdx.z == 0)
    gemm_core<3, 3>(sm, xh, xl, Wqh, Wql, nullptr, qh, cosT, sinT, DMODEL, DMODEL, m0, n0, qs);
  else if (blockIdx.z == 1)
    gemm_core<3, 3>(sm, xh, xl, Wkh, Wkl, nullptr, kh, cosT, sinT, DMODEL, DMODEL, m0, n0, 1.f);
  else
    gemm_core<1, 2>(sm, xh, nullptr, Wvh, nullptr, nullptr, vt, nullptr, nullptr, DMODEL, DMODEL, m0, n0, 1.f);
}

// out = (ch * Woh^T) / 4096  (1-term fp16; dropped terms ~1.5e-4)
__global__ __launch_bounds__(256) void out_kernel(
    const u16* __restrict__ ch, const u16* __restrict__ Woh, float* __restrict__ out) {
  __shared__ u16 sm[2 * 4096];
  gemm_core<1, 0>(sm, ch, nullptr, Woh, nullptr, out, nullptr, nullptr, nullptr, DMODEL, DMODEL,
                  blockIdx.y << 7, blockIdx.x << 7, 1.f / 4096.f);
}

// Flash attention, causal. 1-term fp16 QK (q pre-scaled), f32 online softmax,
// fp16 P and PV with V^T [b][h][d][s]. BQ=128: 512 thr = 8 waves x 16 q-rows
// sharing K/V tiles (BK=64). P in its OWN per-wave LDS buffer (no aliasing,
// no barrier needed for it: strictly within-wave write->read). 2 barriers/iter.
// Register prefetch of tile kt+1; qt descending; ch = 64*ctx fp16.
__global__ __launch_bounds__(512) void attn_kernel(
    const u16* __restrict__ Qh, const u16* __restrict__ Kh,
    const u16* __restrict__ VT, u16* __restrict__ Ch) {
  const int qt = gridDim.x - 1 - blockIdx.x;  // big blocks first
  const int bh = blockIdx.y;
  const int b = bh >> 4, h = bh & 15;
  const int tid = threadIdx.x;
  const int w = tid >> 6, lane = tid & 63;
  const int quad = lane >> 4, l16 = lane & 15;

  __shared__ u16 sKh[64 * 136];   // K-tile [k][d] pitch 136
  __shared__ u16 sVt[128 * 72];   // V^T tile [d][k], pitch 72
  __shared__ u16 sPb[8 * 1088];   // per-wave P, 16 x 68 each (dedicated)
  u16* sP = &sPb[w * 1088];

  const size_t bhbase = (size_t)b * S_CTX * DMODEL + (size_t)h * 128;
  const size_t vtbase = (size_t)bh * 128 * 2048;

  int kr[2], kc[2], vr[2], vc[2];
#pragma unroll
  for (int j = 0; j < 2; ++j) {
    int c = j * 512 + tid;
    kr[j] = c >> 4; kc[j] = (c & 15) << 3;
    vr[j] = c >> 3; vc[j] = (c & 7) << 3;
  }

  // Q fragments; wave w owns q-rows qt*128 + w*16 + [0,16)
  const int qr0 = qt * 128 + w * 16;
  const size_t qoff = bhbase + (size_t)(qr0 + l16) * DMODEL;
  f16x8 qf[4];
#pragma unroll
  for (int c = 0; c < 4; ++c) qf[c] = *(const f16x8*)(Qh + qoff + c * 32 + quad * 8);

  f32x4 oacc[8];
#pragma unroll
  for (int d = 0; d < 8; ++d) oacc[d] = (f32x4){0.f, 0.f, 0.f, 0.f};
  float m_r[4] = {-INFINITY, -INFINITY, -INFINITY, -INFINITY};
  float l_r[4] = {0.f, 0.f, 0.f, 0.f};

  f16x8 rkh[2], rvt[2];
#pragma unroll
  for (int j = 0; j < 2; ++j) {
    rkh[j] = *(const f16x8*)(Kh + bhbase + (size_t)kr[j] * DMODEL + kc[j]);
    rvt[j] = *(const f16x8*)(VT + vtbase + (size_t)vr[j] * 2048 + vc[j]);
  }

  const int nkt = 2 * qt + 2;
  for (int kt = 0; kt < nkt; ++kt) {
    __syncthreads();  // (1) prev iter QK/PV reads of sKh/sVt done
#pragma unroll
    for (int j = 0; j < 2; ++j) {
      *(f16x8*)&sKh[kr[j] * 136 + kc[j]] = rkh[j];
      *(f16x8*)&sVt[vr[j] * 72 + vc[j]] = rvt[j];
    }
    __syncthreads();  // (2) tiles visible
    if (kt + 1 < nkt) {
#pragma unroll
      for (int j = 0; j < 2; ++j) {
        size_t g = bhbase + (size_t)((kt + 1) * 64 + kr[j]) * DMODEL + kc[j];
        rkh[j] = *(const f16x8*)(Kh + g);
        rvt[j] = *(const f16x8*)(VT + vtbase + (size_t)vr[j] * 2048 + (kt + 1) * 64 + vc[j]);
      }
    }

    const bool active = (kt * 64) <= (qr0 + 15);
    if (active) {
      f32x4 sacc[4];
#pragma unroll
      for (int n = 0; n < 4; ++n) sacc[n] = (f32x4){0.f, 0.f, 0.f, 0.f};
#pragma unroll
      for (int n = 0; n < 4; ++n)
#pragma unroll
        for (int c = 0; c < 4; ++c) {
          f16x8 kf = *(const f16x8*)&sKh[(n * 16 + l16) * 136 + c * 32 + quad * 8];
          sacc[n] = __builtin_amdgcn_mfma_f32_16x16x32_f16(qf[c], kf, sacc[n], 0, 0, 0);
        }

      float pm[4][4];
      float rowmax[4] = {-INFINITY, -INFINITY, -INFINITY, -INFINITY};
#pragma unroll
      for (int n = 0; n < 4; ++n)
#pragma unroll
        for (int r = 0; r < 4; ++r) {
          float sc = sacc[n][r];
          int qi = qr0 + quad * 4 + r;
          int ki = kt * 64 + n * 16 + l16;
          if (ki > qi) sc = -INFINITY;
          pm[n][r] = sc;
          rowmax[r] = fmaxf(rowmax[r], sc);
        }
#pragma unroll
      for (int off = 1; off < 16; off <<= 1)
#pragma unroll
        for (int r = 0; r < 4; ++r)
          rowmax[r] = fmaxf(rowmax[r], __shfl_xor(rowmax[r], off, 64));

      float alphav[4];
#pragma unroll
      for (int r = 0; r < 4; ++r) {
        float mnew = fmaxf(m_r[r], rowmax[r]);
        alphav[r] = __expf(m_r[r] - mnew);
        m_r[r] = mnew;
        l_r[r] *= alphav[r];
      }
      float rowsum[4] = {0.f, 0.f, 0.f, 0.f};
#pragma unroll
      for (int n = 0; n < 4; ++n)
#pragma unroll
        for (int r = 0; r < 4; ++r) {
          float p = __expf(pm[n][r] - m_r[r]);
          pm[n][r] = p;
          rowsum[r] += p;
        }
#pragma unroll
      for (int off = 1; off < 16; off <<= 1)
#pragma unroll
        for (int r = 0; r < 4; ++r) rowsum[r] += __shfl_xor(rowsum[r], off, 64);
#pragma unroll
      for (int r = 0; r < 4; ++r) l_r[r] += rowsum[r];

#pragma unroll
      for (int d = 0; d < 8; ++d)
#pragma unroll
        for (int r = 0; r < 4; ++r) oacc[d][r] *= alphav[r];

      // P (C-layout) -> per-wave dedicated LDS region -> A-layout
#pragma unroll
      for (int n = 0; n < 4; ++n)
#pragma unroll
        for (int r = 0; r < 4; ++r)
          sP[(quad * 4 + r) * 68 + n * 16 + l16] = f2h(pm[n][r]);

      // O += P.V
#pragma unroll
      for (int c = 0; c < 2; ++c) {
        f16x8 pf = *(const f16x8*)&sP[l16 * 68 + c * 32 + quad * 8];
#pragma unroll
        for (int d = 0; d < 8; ++d) {
          f16x8 vf = *(const f16x8*)&sVt[(d * 16 + l16) * 72 + c * 32 + quad * 8];
          oacc[d] = __builtin_amdgcn_mfma_f32_16x16x32_f16(pf, vf, oacc[d], 0, 0, 0);
        }
      }
    }
  }

  float invl[4];
#pragma unroll
  for (int r = 0; r < 4; ++r) invl[r] = 1.f / l_r[r];
#pragma unroll
  for (int d = 0; d < 8; ++d)
#pragma unroll
    for (int r = 0; r < 4; ++r) {
      int row = qr0 + quad * 4 + r;
      Ch[bhbase + (size_t)row * DMODEL + d * 16 + l16] = f2h(oacc[d][r] * invl[r]);
    }
}

extern "C" void kernel_launch(void* const* d_in, const int* in_sizes, int n_in,
                              void* d_out, int out_size, void* d_ws, size_t ws_size,
                              hipStream_t stream) {
  const float* x    = (const float*)d_in[0];
  const float* Wq   = (const float*)d_in[1];
  const float* Wk   = (const float*)d_in[2];
  const float* Wv   = (const float*)d_in[3];
  const float* Wo   = (const float*)d_in[4];
  const float* cosT = (const float*)d_in[5];
  const float* sinT = (const float*)d_in[6];
  float* out = (float*)d_out;

  const size_t NX = 8388608;   // 2*2048*2048
  const size_t NW = 4194304;   // 2048*2048
  u16* p = (u16*)d_ws;
  u16* xh  = p; p += NX;  u16* xl  = p; p += NX;
  u16* Wqh = p; p += NW;  u16* Wql = p; p += NW;
  u16* Wkh = p; p += NW;  u16* Wkl = p; p += NW;
  u16* Wvh = p; p += NW;  u16* Woh = p; p += NW;
  u16* qh  = p; p += NX;  u16* kh  = p; p += NX;
  u16* vt  = p; p += NX;
  u16* ch  = p; p += NX;
  // ~150 MiB of d_ws

  split_all<<<98304, 256, 0, stream>>>(x, Wq, Wk, Wv, Wo,
                                       xh, xl, Wqh, Wql, Wkh, Wkl, Wvh, Woh);

  qkv_kernel<<<dim3(16, 32, 3), 256, 0, stream>>>(xh, xl, Wqh, Wql, Wkh, Wkl, Wvh,
                                                  cosT, sinT, qh, kh, vt);

  attn_kernel<<<dim3(16, 32), 512, 0, stream>>>(qh, kh, vt, ch);

  out_kernel<<<dim3(16, 32), 256, 0, stream>>>(ch, Woh, out);
}

// Round 4
// 632.054 us; speedup vs baseline: 1.2959x; 1.0238x over previous
//
#include <hip/hip_runtime.h>

typedef unsigned short u16;
typedef __attribute__((ext_vector_type(8))) _Float16 f16x8;
typedef __attribute__((ext_vector_type(4))) float f32x4;

#define S_CTX 2048
#define DMODEL 2048

#define WAITVM(N) asm volatile("s_waitcnt vmcnt(" #N ")" ::: "memory")
#define SBAR() __builtin_amdgcn_s_barrier()

__device__ __forceinline__ u16 f2h(float f) {
  _Float16 h = (_Float16)f; u16 u; __builtin_memcpy(&u, &h, 2); return u;
}
__device__ __forceinline__ float h2f(u16 u) {
  _Float16 h; __builtin_memcpy(&h, &u, 2); return (float)h;
}
__device__ __forceinline__ void gload16(const u16* g, u16* l) {
  __builtin_amdgcn_global_load_lds(
      (const __attribute__((address_space(1))) unsigned int*)g,
      (__attribute__((address_space(3))) unsigned int*)l, 16, 0, 0);
}

// One fused split pass. x -> fp16 pair (no scale). Wq,Wk -> fp16 pair (x64).
// Wv,Wo -> fp16 single (x64). Scales folded out downstream (q-prescale, /4096).
__global__ void split_all(const float* __restrict__ x, const float* __restrict__ Wq,
                          const float* __restrict__ Wk, const float* __restrict__ Wv,
                          const float* __restrict__ Wo,
                          u16* xh, u16* xl, u16* Wqh, u16* Wql,
                          u16* Wkh, u16* Wkl, u16* Wvh, u16* Woh) {
  size_t i = (size_t)blockIdx.x * 256 + threadIdx.x;
  const size_t NX = 8388608, NW = 4194304;
  if (i < NX) {
    float v = x[i];
    u16 h = f2h(v);
    xh[i] = h; xl[i] = f2h(v - h2f(h));
  } else {
    size_t j = i - NX;
    int wsel = (int)(j >> 22);
    size_t o = j & (NW - 1);
    if (wsel == 0) { float v = Wq[o] * 64.f; u16 h = f2h(v); Wqh[o] = h; Wql[o] = f2h(v - h2f(h)); }
    else if (wsel == 1) { float v = Wk[o] * 64.f; u16 h = f2h(v); Wkh[o] = h; Wkl[o] = f2h(v - h2f(h)); }
    else if (wsel == 2) { Wvh[o] = f2h(Wv[o] * 64.f); }
    else { Woh[o] = f2h(Wo[o] * 64.f); }
  }
}

// ---------------------------------------------------------------------------
// C[M,N] = A * B^T, fp16 MFMA, 128x128 tile, 256 thr = 4 waves (2M x 2N),
// BK=32. Round-3 verified staging (coalesced 16x64B rows + coalescing-neutral
// XOR chunk swizzle; bit-identical data) + counted-vmcnt pipeline:
//
//   NT==3: double-buffered (2 x 16K u16). Per K-step, 2 phases:
//     ph1: WAITVM(4) [h(t) landed]  SBAR  ds_read ah,bh  stage h(t+1)
//          16 MFMA (ah*bh)
//     ph2: WAITVM(4) [l(t) landed]  SBAR  ds_read bl,al  stage l(t+1)
//          32 MFMA (ah*bl, al*bh)
//     vmcnt oscillates 8 -> 4: never drained to 0 in the main loop.
//   NT==1: triple-buffered (3 x 8K u16), depth-2 prefetch, WAITVM(4)/step.
//
// Buffer safety: a stage at step t writes the buffer read at step t-1; the
// barrier at the top of the phase guarantees all waves completed those reads
// (ds_read -> MFMA data-dep forces completion before loop-back). Visibility:
// each producer's WAITVM retires its own gload_lds; the SBAR after it
// publishes to consumers. Per-acc MFMA order (hh,hl,lh) is unchanged vs
// round 3 -> bit-identical output.
//
// NT==3: AhBh+AhBl+AlBh   NT==1: AhBh
// MODE 0: f32*oscale -> Cf
// MODE 2: V^T fp16 -> Ch  ([b][h][d][s])
// MODE 3: fused RoPE -> fp16 single Ch (tile = one full head; d<->d+64
//         exchanged through LDS per i-block; oscale folds the q prescale).
// ---------------------------------------------------------------------------
template <int NT, int MODE>
__device__ __forceinline__ void gemm_core(
    u16* sm, const u16* __restrict__ Am, const u16* __restrict__ Alm,
    const u16* __restrict__ Bm, const u16* __restrict__ Blm,
    float* __restrict__ Cf, u16* __restrict__ Ch,
    const float* __restrict__ cosT, const float* __restrict__ sinT,
    int N, int K, int m0, int n0, float oscale) {
  const int tid = threadIdx.x;
  const int w = tid >> 6, lane = tid & 63;
  const int quad = lane >> 4, l16 = lane & 15;
  const int wm = (w >> 1) << 6, wn = (w & 1) << 6;
  const int lrow = lane >> 2, lcol = (lane & 3) << 3;
  // source-side swizzle (u16 units): chunk ^= (row>>1)&3  (coalescing-neutral)
  const int lcs = lcol ^ (((lrow >> 1) & 3) << 3);
  // read-side swizzle: same involution
  const int qsw = (quad << 3) ^ (((l16 >> 1) & 3) << 3);

  // stage h-parts (Ah,Bh) of one K-tile into buffer at base bufb (u16 units)
  auto stageH = [&](int bufb, int k0) {
#pragma unroll
    for (int j = 0; j < 2; ++j) {
      int r = w * 32 + j * 16 + lrow;
      int lb = bufb + (w * 32 + j * 16) * 32;
      size_t ga = (size_t)(m0 + r) * K + k0 + lcs;
      size_t gb = (size_t)(n0 + r) * K + k0 + lcs;
      gload16(Am + ga, &sm[lb]);
      gload16(Bm + gb, &sm[lb + 4096]);
    }
  };
  // stage l-parts (Bl,Al)
  auto stageL = [&](int bufb, int k0) {
#pragma unroll
    for (int j = 0; j < 2; ++j) {
      int r = w * 32 + j * 16 + lrow;
      int lb = bufb + (w * 32 + j * 16) * 32;
      size_t ga = (size_t)(m0 + r) * K + k0 + lcs;
      size_t gb = (size_t)(n0 + r) * K + k0 + lcs;
      gload16(Blm + gb, &sm[lb + 8192]);
      gload16(Alm + ga, &sm[lb + 12288]);
    }
  };

  f32x4 acc[4][4];
#pragma unroll
  for (int i = 0; i < 4; ++i)
#pragma unroll
    for (int n = 0; n < 4; ++n) acc[i][n] = (f32x4){0.f, 0.f, 0.f, 0.f};

  const int NTL = K >> 5;

  if (NT == 3) {
    stageH(0, 0);   // 4 loads
    stageL(0, 0);   // 4 loads -> 8 outstanding
    for (int t = 0; t < NTL; ++t) {
      const int cur = (t & 1) << 14;      // 0 / 16384
      const int nxt = 16384 - cur;
      const int k0n = (t + 1) << 5;
      const bool more = (t + 1 < NTL);

      // ---- phase 1: Ah x Bh ----
      WAITVM(4);    // h(t) landed (l(t) stays in flight)
      SBAR();
      f16x8 ah[4], bh[4];
#pragma unroll
      for (int i = 0; i < 4; ++i)
        ah[i] = *(const f16x8*)&sm[cur + (wm + i * 16 + l16) * 32 + qsw];
#pragma unroll
      for (int n = 0; n < 4; ++n)
        bh[n] = *(const f16x8*)&sm[cur + 4096 + (wn + n * 16 + l16) * 32 + qsw];
      if (more) stageH(nxt, k0n);
#pragma unroll
      for (int i = 0; i < 4; ++i)
#pragma unroll
        for (int n = 0; n < 4; ++n)
          acc[i][n] = __builtin_amdgcn_mfma_f32_16x16x32_f16(ah[i], bh[n], acc[i][n], 0, 0, 0);

      // ---- phase 2: Ah x Bl + Al x Bh ----
      if (more) { WAITVM(4); } else { WAITVM(0); }  // l(t) landed
      SBAR();
      f16x8 bl[4], al[4];
#pragma unroll
      for (int n = 0; n < 4; ++n)
        bl[n] = *(const f16x8*)&sm[cur + 8192 + (wn + n * 16 + l16) * 32 + qsw];
#pragma unroll
      for (int i = 0; i < 4; ++i)
        al[i] = *(const f16x8*)&sm[cur + 12288 + (wm + i * 16 + l16) * 32 + qsw];
      if (more) stageL(nxt, k0n);
#pragma unroll
      for (int i = 0; i < 4; ++i)
#pragma unroll
        for (int n = 0; n < 4; ++n) {
          acc[i][n] = __builtin_amdgcn_mfma_f32_16x16x32_f16(ah[i], bl[n], acc[i][n], 0, 0, 0);
          acc[i][n] = __builtin_amdgcn_mfma_f32_16x16x32_f16(al[i], bh[n], acc[i][n], 0, 0, 0);
        }
    }
  } else {
    stageH(0, 0);       // tile 0
    stageH(8192, 32);   // tile 1 -> 8 outstanding
    for (int t = 0; t < NTL; ++t) {
      const int cur = (t % 3) * 8192;
      if (t + 1 < NTL) { WAITVM(4); } else { WAITVM(0); }  // tile t landed
      SBAR();
      f16x8 ah[4], bh[4];
#pragma unroll
      for (int i = 0; i < 4; ++i)
        ah[i] = *(const f16x8*)&sm[cur + (wm + i * 16 + l16) * 32 + qsw];
#pragma unroll
      for (int n = 0; n < 4; ++n)
        bh[n] = *(const f16x8*)&sm[cur + 4096 + (wn + n * 16 + l16) * 32 + qsw];
      if (t + 2 < NTL) stageH(((t + 2) % 3) * 8192, (t + 2) << 5);
#pragma unroll
      for (int i = 0; i < 4; ++i)
#pragma unroll
        for (int n = 0; n < 4; ++n)
          acc[i][n] = __builtin_amdgcn_mfma_f32_16x16x32_f16(ah[i], bh[n], acc[i][n], 0, 0, 0);
    }
  }

  // epilogue: C/D layout row=(lane>>4)*4+r, col=lane&15
  if (MODE == 3) {
    // fused RoPE: tile cols n0..n0+127 are exactly one head (d = local col).
    float* fs = (float*)sm;  // 2 pairs x 16 rows x 128 cols f32 = 16 KiB
    const int p = w >> 1;
#pragma unroll
    for (int i = 0; i < 4; ++i) {
      __syncthreads();  // prev i-block reads (or K-loop LDS reads) done
#pragma unroll
      for (int n = 0; n < 4; ++n)
#pragma unroll
        for (int r = 0; r < 4; ++r)
          fs[p * 2048 + (quad * 4 + r) * 128 + wn + n * 16 + l16] = acc[i][n][r];
      __syncthreads();
#pragma unroll
      for (int n = 0; n < 4; ++n) {
        const int col = wn + n * 16 + l16;
        const int cc = col ^ 64;
        const float sgn = (col < 64) ? -1.f : 1.f;
#pragma unroll
        for (int r = 0; r < 4; ++r) {
          const int row16 = quad * 4 + r;
          const int grow = m0 + wm + i * 16 + row16;
          const int s = grow & (S_CTX - 1);
          const float c = cosT[s * 128 + col];
          const float sn = sinT[s * 128 + col];
          const float x = fs[p * 2048 + row16 * 128 + col];
          const float xp = fs[p * 2048 + row16 * 128 + cc];
          Ch[(size_t)grow * N + n0 + col] = f2h((x * c + sgn * xp * sn) * oscale);
        }
      }
    }
    return;
  }
#pragma unroll
  for (int i = 0; i < 4; ++i)
#pragma unroll
    for (int n = 0; n < 4; ++n) {
      const int row0 = m0 + wm + i * 16 + quad * 4;
      const int col = n0 + wn + n * 16 + l16;
      if (MODE == 0) {
#pragma unroll
        for (int r = 0; r < 4; ++r) Cf[(size_t)(row0 + r) * N + col] = acc[i][n][r] * oscale;
      } else {
        int brow = row0 >> 11, s0 = row0 & 2047;
        int hh = col >> 7, d = col & 127;
        ushort4 pk;
        pk.x = f2h(acc[i][n][0]);
        pk.y = f2h(acc[i][n][1]);
        pk.z = f2h(acc[i][n][2]);
        pk.w = f2h(acc[i][n][3]);
        *(ushort4*)(Ch + ((size_t)(brow * 16 + hh) * 128 + d) * 2048 + s0) = pk;
      }
    }
}

// Fused QKV projection + RoPE: grid (16, 32, 3).
// z=0: Q (3-term, rope + qs prescale); z=1: K (3-term, rope); z=2: V (1-term, V^T out)
__global__ __launch_bounds__(256) void qkv_kernel(
    const u16* __restrict__ xh, const u16* __restrict__ xl,
    const u16* __restrict__ Wqh, const u16* __restrict__ Wql,
    const u16* __restrict__ Wkh, const u16* __restrict__ Wkl,
    const u16* __restrict__ Wvh,
    const float* __restrict__ cosT, const float* __restrict__ sinT,
    u16* qh, u16* kh, u16* vt) {
  __shared__ u16 sm[32768];  // 64 KiB: 2 x 16K u16 (NT3 dbuf) / 3 x 8K (NT1)
  const int m0 = blockIdx.y << 7, n0 = blockIdx.x << 7;
  const float qs = 0.002762135864009951f;  // sqrt(128)/4096
  if (blockIdx.z == 0)
    gemm_core<3, 3>(sm, xh, xl, Wqh, Wql, nullptr, qh, cosT, sinT, DMODEL, DMODEL, m0, n0, qs);
  else if (blockIdx.z == 1)
    gemm_core<3, 3>(sm, xh, xl, Wkh, Wkl, nullptr, kh, cosT, sinT, DMODEL, DMODEL, m0, n0, 1.f);
  else
    gemm_core<1, 2>(sm, xh, nullptr, Wvh, nullptr, nullptr, vt, nullptr, nullptr, DMODEL, DMODEL, m0, n0, 1.f);
}

// out = (ch * Woh^T) / 4096  (1-term fp16; dropped terms ~1.5e-4)
__global__ __launch_bounds__(256) void out_kernel(
    const u16* __restrict__ ch, const u16* __restrict__ Woh, float* __restrict__ out) {
  __shared__ u16 sm[24576];  // 48 KiB: 3 x 8K u16
  gemm_core<1, 0>(sm, ch, nullptr, Woh, nullptr, out, nullptr, nullptr, nullptr, DMODEL, DMODEL,
                  blockIdx.y << 7, blockIdx.x << 7, 1.f / 4096.f);
}

// Flash attention, causal. 1-term fp16 QK (q pre-scaled), f32 online softmax,
// fp16 P and PV with V^T [b][h][d][s]. BQ=128: 512 thr = 8 waves x 16 q-rows
// sharing K/V tiles (BK=64). P in its OWN per-wave LDS buffer (no aliasing,
// no barrier needed for it: strictly within-wave write->read). 2 barriers/iter.
// Register prefetch of tile kt+1; qt descending; ch = 64*ctx fp16.
__global__ __launch_bounds__(512) void attn_kernel(
    const u16* __restrict__ Qh, const u16* __restrict__ Kh,
    const u16* __restrict__ VT, u16* __restrict__ Ch) {
  const int qt = gridDim.x - 1 - blockIdx.x;  // big blocks first
  const int bh = blockIdx.y;
  const int b = bh >> 4, h = bh & 15;
  const int tid = threadIdx.x;
  const int w = tid >> 6, lane = tid & 63;
  const int quad = lane >> 4, l16 = lane & 15;

  __shared__ u16 sKh[64 * 136];   // K-tile [k][d] pitch 136
  __shared__ u16 sVt[128 * 72];   // V^T tile [d][k], pitch 72
  __shared__ u16 sPb[8 * 1088];   // per-wave P, 16 x 68 each (dedicated)
  u16* sP = &sPb[w * 1088];

  const size_t bhbase = (size_t)b * S_CTX * DMODEL + (size_t)h * 128;
  const size_t vtbase = (size_t)bh * 128 * 2048;

  int kr[2], kc[2], vr[2], vc[2];
#pragma unroll
  for (int j = 0; j < 2; ++j) {
    int c = j * 512 + tid;
    kr[j] = c >> 4; kc[j] = (c & 15) << 3;
    vr[j] = c >> 3; vc[j] = (c & 7) << 3;
  }

  // Q fragments; wave w owns q-rows qt*128 + w*16 + [0,16)
  const int qr0 = qt * 128 + w * 16;
  const size_t qoff = bhbase + (size_t)(qr0 + l16) * DMODEL;
  f16x8 qf[4];
#pragma unroll
  for (int c = 0; c < 4; ++c) qf[c] = *(const f16x8*)(Qh + qoff + c * 32 + quad * 8);

  f32x4 oacc[8];
#pragma unroll
  for (int d = 0; d < 8; ++d) oacc[d] = (f32x4){0.f, 0.f, 0.f, 0.f};
  float m_r[4] = {-INFINITY, -INFINITY, -INFINITY, -INFINITY};
  float l_r[4] = {0.f, 0.f, 0.f, 0.f};

  f16x8 rkh[2], rvt[2];
#pragma unroll
  for (int j = 0; j < 2; ++j) {
    rkh[j] = *(const f16x8*)(Kh + bhbase + (size_t)kr[j] * DMODEL + kc[j]);
    rvt[j] = *(const f16x8*)(VT + vtbase + (size_t)vr[j] * 2048 + vc[j]);
  }

  const int nkt = 2 * qt + 2;
  for (int kt = 0; kt < nkt; ++kt) {
    __syncthreads();  // (1) prev iter QK/PV reads of sKh/sVt done
#pragma unroll
    for (int j = 0; j < 2; ++j) {
      *(f16x8*)&sKh[kr[j] * 136 + kc[j]] = rkh[j];
      *(f16x8*)&sVt[vr[j] * 72 + vc[j]] = rvt[j];
    }
    __syncthreads();  // (2) tiles visible
    if (kt + 1 < nkt) {
#pragma unroll
      for (int j = 0; j < 2; ++j) {
        size_t g = bhbase + (size_t)((kt + 1) * 64 + kr[j]) * DMODEL + kc[j];
        rkh[j] = *(const f16x8*)(Kh + g);
        rvt[j] = *(const f16x8*)(VT + vtbase + (size_t)vr[j] * 2048 + (kt + 1) * 64 + vc[j]);
      }
    }

    const bool active = (kt * 64) <= (qr0 + 15);
    if (active) {
      f32x4 sacc[4];
#pragma unroll
      for (int n = 0; n < 4; ++n) sacc[n] = (f32x4){0.f, 0.f, 0.f, 0.f};
#pragma unroll
      for (int n = 0; n < 4; ++n)
#pragma unroll
        for (int c = 0; c < 4; ++c) {
          f16x8 kf = *(const f16x8*)&sKh[(n * 16 + l16) * 136 + c * 32 + quad * 8];
          sacc[n] = __builtin_amdgcn_mfma_f32_16x16x32_f16(qf[c], kf, sacc[n], 0, 0, 0);
        }

      float pm[4][4];
      float rowmax[4] = {-INFINITY, -INFINITY, -INFINITY, -INFINITY};
#pragma unroll
      for (int n = 0; n < 4; ++n)
#pragma unroll
        for (int r = 0; r < 4; ++r) {
          float sc = sacc[n][r];
          int qi = qr0 + quad * 4 + r;
          int ki = kt * 64 + n * 16 + l16;
          if (ki > qi) sc = -INFINITY;
          pm[n][r] = sc;
          rowmax[r] = fmaxf(rowmax[r], sc);
        }
#pragma unroll
      for (int off = 1; off < 16; off <<= 1)
#pragma unroll
        for (int r = 0; r < 4; ++r)
          rowmax[r] = fmaxf(rowmax[r], __shfl_xor(rowmax[r], off, 64));

      float alphav[4];
#pragma unroll
      for (int r = 0; r < 4; ++r) {
        float mnew = fmaxf(m_r[r], rowmax[r]);
        alphav[r] = __expf(m_r[r] - mnew);
        m_r[r] = mnew;
        l_r[r] *= alphav[r];
      }
      float rowsum[4] = {0.f, 0.f, 0.f, 0.f};
#pragma unroll
      for (int n = 0; n < 4; ++n)
#pragma unroll
        for (int r = 0; r < 4; ++r) {
          float p = __expf(pm[n][r] - m_r[r]);
          pm[n][r] = p;
          rowsum[r] += p;
        }
#pragma unroll
      for (int off = 1; off < 16; off <<= 1)
#pragma unroll
        for (int r = 0; r < 4; ++r) rowsum[r] += __shfl_xor(rowsum[r], off, 64);
#pragma unroll
      for (int r = 0; r < 4; ++r) l_r[r] += rowsum[r];

#pragma unroll
      for (int d = 0; d < 8; ++d)
#pragma unroll
        for (int r = 0; r < 4; ++r) oacc[d][r] *= alphav[r];

      // P (C-layout) -> per-wave dedicated LDS region -> A-layout
#pragma unroll
      for (int n = 0; n < 4; ++n)
#pragma unroll
        for (int r = 0; r < 4; ++r)
          sP[(quad * 4 + r) * 68 + n * 16 + l16] = f2h(pm[n][r]);

      // O += P.V
#pragma unroll
      for (int c = 0; c < 2; ++c) {
        f16x8 pf = *(const f16x8*)&sP[l16 * 68 + c * 32 + quad * 8];
#pragma unroll
        for (int d = 0; d < 8; ++d) {
          f16x8 vf = *(const f16x8*)&sVt[(d * 16 + l16) * 72 + c * 32 + quad * 8];
          oacc[d] = __builtin_amdgcn_mfma_f32_16x16x32_f16(pf, vf, oacc[d], 0, 0, 0);
        }
      }
    }
  }

  float invl[4];
#pragma unroll
  for (int r = 0; r < 4; ++r) invl[r] = 1.f / l_r[r];
#pragma unroll
  for (int d = 0; d < 8; ++d)
#pragma unroll
    for (int r = 0; r < 4; ++r) {
      int row = qr0 + quad * 4 + r;
      Ch[bhbase + (size_t)row * DMODEL + d * 16 + l16] = f2h(oacc[d][r] * invl[r]);
    }
}

extern "C" void kernel_launch(void* const* d_in, const int* in_sizes, int n_in,
                              void* d_out, int out_size, void* d_ws, size_t ws_size,
                              hipStream_t stream) {
  const float* x    = (const float*)d_in[0];
  const float* Wq   = (const float*)d_in[1];
  const float* Wk   = (const float*)d_in[2];
  const float* Wv   = (const float*)d_in[3];
  const float* Wo   = (const float*)d_in[4];
  const float* cosT = (const float*)d_in[5];
  const float* sinT = (const float*)d_in[6];
  float* out = (float*)d_out;

  const size_t NX = 8388608;   // 2*2048*2048
  const size_t NW = 4194304;   // 2048*2048
  u16* p = (u16*)d_ws;
  u16* xh  = p; p += NX;  u16* xl  = p; p += NX;
  u16* Wqh = p; p += NW;  u16* Wql = p; p += NW;
  u16* Wkh = p; p += NW;  u16* Wkl = p; p += NW;
  u16* Wvh = p; p += NW;  u16* Woh = p; p += NW;
  u16* qh  = p; p += NX;  u16* kh  = p; p += NX;
  u16* vt  = p; p += NX;
  u16* ch  = p; p += NX;
  // ~150 MiB of d_ws

  split_all<<<98304, 256, 0, stream>>>(x, Wq, Wk, Wv, Wo,
                                       xh, xl, Wqh, Wql, Wkh, Wkl, Wvh, Woh);

  qkv_kernel<<<dim3(16, 32, 3), 256, 0, stream>>>(xh, xl, Wqh, Wql, Wkh, Wkl, Wvh,
                                                  cosT, sinT, qh, kh, vt);

  attn_kernel<<<dim3(16, 32), 512, 0, stream>>>(qh, kh, vt, ch);

  out_kernel<<<dim3(16, 32), 256, 0, stream>>>(ch, Woh, out);
}

// Round 5
// 555.855 us; speedup vs baseline: 1.4736x; 1.1371x over previous
//
#include <hip/hip_runtime.h>

typedef unsigned short u16;
typedef __attribute__((ext_vector_type(8))) _Float16 f16x8;
typedef __attribute__((ext_vector_type(4))) float f32x4;

#define S_CTX 2048
#define DMODEL 2048

#define WAITVM(N) asm volatile("s_waitcnt vmcnt(" #N ")" ::: "memory")
#define SBAR() __builtin_amdgcn_s_barrier()

__device__ __forceinline__ u16 f2h(float f) {
  _Float16 h = (_Float16)f; u16 u; __builtin_memcpy(&u, &h, 2); return u;
}
__device__ __forceinline__ float h2f(u16 u) {
  _Float16 h; __builtin_memcpy(&h, &u, 2); return (float)h;
}
__device__ __forceinline__ void gload16(const u16* g, u16* l) {
  __builtin_amdgcn_global_load_lds(
      (const __attribute__((address_space(1))) unsigned int*)g,
      (__attribute__((address_space(3))) unsigned int*)l, 16, 0, 0);
}

// One fused split pass. x -> fp16 pair (no scale). Wq,Wk -> fp16 pair (x64).
// Wv,Wo -> fp16 single (x64). Scales folded out downstream (q-prescale, /4096).
__global__ void split_all(const float* __restrict__ x, const float* __restrict__ Wq,
                          const float* __restrict__ Wk, const float* __restrict__ Wv,
                          const float* __restrict__ Wo,
                          u16* xh, u16* xl, u16* Wqh, u16* Wql,
                          u16* Wkh, u16* Wkl, u16* Wvh, u16* Woh) {
  size_t i = (size_t)blockIdx.x * 256 + threadIdx.x;
  const size_t NX = 8388608, NW = 4194304;
  if (i < NX) {
    float v = x[i];
    u16 h = f2h(v);
    xh[i] = h; xl[i] = f2h(v - h2f(h));
  } else {
    size_t j = i - NX;
    int wsel = (int)(j >> 22);
    size_t o = j & (NW - 1);
    if (wsel == 0) { float v = Wq[o] * 64.f; u16 h = f2h(v); Wqh[o] = h; Wql[o] = f2h(v - h2f(h)); }
    else if (wsel == 1) { float v = Wk[o] * 64.f; u16 h = f2h(v); Wkh[o] = h; Wkl[o] = f2h(v - h2f(h)); }
    else if (wsel == 2) { Wvh[o] = f2h(Wv[o] * 64.f); }
    else { Woh[o] = f2h(Wo[o] * 64.f); }
  }
}

// ---------------------------------------------------------------------------
// C[M,N] = A * B^T, fp16 MFMA, 128x128 tile, 256 thr = 4 waves (2M x 2N),
// BK=32. Round-3 verified staging (coalesced 16x64B rows + coalescing-neutral
// XOR chunk swizzle; bit-identical data) + counted-vmcnt pipeline:
//
//   NT==3: double-buffered (2 x 16K u16). Per K-step, 2 phases:
//     ph1: WAITVM(4) [h(t) landed]  SBAR  ds_read ah,bh  stage h(t+1)
//          16 MFMA (ah*bh)
//     ph2: WAITVM(4) [l(t) landed]  SBAR  ds_read bl,al  stage l(t+1)
//          32 MFMA (ah*bl, al*bh)
//     vmcnt oscillates 8 -> 4: never drained to 0 in the main loop.
//   NT==1: triple-buffered (3 x 8K u16), depth-2 prefetch, WAITVM(4)/step.
//
// Buffer safety: a stage at step t writes the buffer read at step t-1; the
// barrier at the top of the phase guarantees all waves completed those reads
// (ds_read -> MFMA data-dep forces completion before loop-back). Visibility:
// each producer's WAITVM retires its own gload_lds; the SBAR after it
// publishes to consumers. Per-acc MFMA order (hh,hl,lh) is unchanged vs
// round 3 -> bit-identical output.
//
// NT==3: AhBh+AhBl+AlBh   NT==1: AhBh
// MODE 0: f32*oscale -> Cf
// MODE 2: V^T fp16 -> Ch  ([b][h][d][s])
// MODE 3: fused RoPE -> fp16 single Ch (tile = one full head; d<->d+64
//         exchanged through LDS per i-block; oscale folds the q prescale).
// ---------------------------------------------------------------------------
template <int NT, int MODE>
__device__ __forceinline__ void gemm_core(
    u16* sm, const u16* __restrict__ Am, const u16* __restrict__ Alm,
    const u16* __restrict__ Bm, const u16* __restrict__ Blm,
    float* __restrict__ Cf, u16* __restrict__ Ch,
    const float* __restrict__ cosT, const float* __restrict__ sinT,
    int N, int K, int m0, int n0, float oscale) {
  const int tid = threadIdx.x;
  const int w = tid >> 6, lane = tid & 63;
  const int quad = lane >> 4, l16 = lane & 15;
  const int wm = (w >> 1) << 6, wn = (w & 1) << 6;
  const int lrow = lane >> 2, lcol = (lane & 3) << 3;
  // source-side swizzle (u16 units): chunk ^= (row>>1)&3  (coalescing-neutral)
  const int lcs = lcol ^ (((lrow >> 1) & 3) << 3);
  // read-side swizzle: same involution
  const int qsw = (quad << 3) ^ (((l16 >> 1) & 3) << 3);

  // stage h-parts (Ah,Bh) of one K-tile into buffer at base bufb (u16 units)
  auto stageH = [&](int bufb, int k0) {
#pragma unroll
    for (int j = 0; j < 2; ++j) {
      int r = w * 32 + j * 16 + lrow;
      int lb = bufb + (w * 32 + j * 16) * 32;
      size_t ga = (size_t)(m0 + r) * K + k0 + lcs;
      size_t gb = (size_t)(n0 + r) * K + k0 + lcs;
      gload16(Am + ga, &sm[lb]);
      gload16(Bm + gb, &sm[lb + 4096]);
    }
  };
  // stage l-parts (Bl,Al)
  auto stageL = [&](int bufb, int k0) {
#pragma unroll
    for (int j = 0; j < 2; ++j) {
      int r = w * 32 + j * 16 + lrow;
      int lb = bufb + (w * 32 + j * 16) * 32;
      size_t ga = (size_t)(m0 + r) * K + k0 + lcs;
      size_t gb = (size_t)(n0 + r) * K + k0 + lcs;
      gload16(Blm + gb, &sm[lb + 8192]);
      gload16(Alm + ga, &sm[lb + 12288]);
    }
  };

  f32x4 acc[4][4];
#pragma unroll
  for (int i = 0; i < 4; ++i)
#pragma unroll
    for (int n = 0; n < 4; ++n) acc[i][n] = (f32x4){0.f, 0.f, 0.f, 0.f};

  const int NTL = K >> 5;

  if (NT == 3) {
    stageH(0, 0);   // 4 loads
    stageL(0, 0);   // 4 loads -> 8 outstanding
    for (int t = 0; t < NTL; ++t) {
      const int cur = (t & 1) << 14;      // 0 / 16384
      const int nxt = 16384 - cur;
      const int k0n = (t + 1) << 5;
      const bool more = (t + 1 < NTL);

      // ---- phase 1: Ah x Bh ----
      WAITVM(4);    // h(t) landed (l(t) stays in flight)
      SBAR();
      f16x8 ah[4], bh[4];
#pragma unroll
      for (int i = 0; i < 4; ++i)
        ah[i] = *(const f16x8*)&sm[cur + (wm + i * 16 + l16) * 32 + qsw];
#pragma unroll
      for (int n = 0; n < 4; ++n)
        bh[n] = *(const f16x8*)&sm[cur + 4096 + (wn + n * 16 + l16) * 32 + qsw];
      if (more) stageH(nxt, k0n);
#pragma unroll
      for (int i = 0; i < 4; ++i)
#pragma unroll
        for (int n = 0; n < 4; ++n)
          acc[i][n] = __builtin_amdgcn_mfma_f32_16x16x32_f16(ah[i], bh[n], acc[i][n], 0, 0, 0);

      // ---- phase 2: Ah x Bl + Al x Bh ----
      if (more) { WAITVM(4); } else { WAITVM(0); }  // l(t) landed
      SBAR();
      f16x8 bl[4], al[4];
#pragma unroll
      for (int n = 0; n < 4; ++n)
        bl[n] = *(const f16x8*)&sm[cur + 8192 + (wn + n * 16 + l16) * 32 + qsw];
#pragma unroll
      for (int i = 0; i < 4; ++i)
        al[i] = *(const f16x8*)&sm[cur + 12288 + (wm + i * 16 + l16) * 32 + qsw];
      if (more) stageL(nxt, k0n);
#pragma unroll
      for (int i = 0; i < 4; ++i)
#pragma unroll
        for (int n = 0; n < 4; ++n) {
          acc[i][n] = __builtin_amdgcn_mfma_f32_16x16x32_f16(ah[i], bl[n], acc[i][n], 0, 0, 0);
          acc[i][n] = __builtin_amdgcn_mfma_f32_16x16x32_f16(al[i], bh[n], acc[i][n], 0, 0, 0);
        }
    }
  } else {
    stageH(0, 0);       // tile 0
    stageH(8192, 32);   // tile 1 -> 8 outstanding
    for (int t = 0; t < NTL; ++t) {
      const int cur = (t % 3) * 8192;
      if (t + 1 < NTL) { WAITVM(4); } else { WAITVM(0); }  // tile t landed
      SBAR();
      f16x8 ah[4], bh[4];
#pragma unroll
      for (int i = 0; i < 4; ++i)
        ah[i] = *(const f16x8*)&sm[cur + (wm + i * 16 + l16) * 32 + qsw];
#pragma unroll
      for (int n = 0; n < 4; ++n)
        bh[n] = *(const f16x8*)&sm[cur + 4096 + (wn + n * 16 + l16) * 32 + qsw];
      if (t + 2 < NTL) stageH(((t + 2) % 3) * 8192, (t + 2) << 5);
#pragma unroll
      for (int i = 0; i < 4; ++i)
#pragma unroll
        for (int n = 0; n < 4; ++n)
          acc[i][n] = __builtin_amdgcn_mfma_f32_16x16x32_f16(ah[i], bh[n], acc[i][n], 0, 0, 0);
    }
  }

  // epilogue: C/D layout row=(lane>>4)*4+r, col=lane&15
  if (MODE == 3) {
    // fused RoPE: tile cols n0..n0+127 are exactly one head (d = local col).
    float* fs = (float*)sm;  // 2 pairs x 16 rows x 128 cols f32 = 16 KiB
    const int p = w >> 1;
#pragma unroll
    for (int i = 0; i < 4; ++i) {
      __syncthreads();  // prev i-block reads (or K-loop LDS reads) done
#pragma unroll
      for (int n = 0; n < 4; ++n)
#pragma unroll
        for (int r = 0; r < 4; ++r)
          fs[p * 2048 + (quad * 4 + r) * 128 + wn + n * 16 + l16] = acc[i][n][r];
      __syncthreads();
#pragma unroll
      for (int n = 0; n < 4; ++n) {
        const int col = wn + n * 16 + l16;
        const int cc = col ^ 64;
        const float sgn = (col < 64) ? -1.f : 1.f;
#pragma unroll
        for (int r = 0; r < 4; ++r) {
          const int row16 = quad * 4 + r;
          const int grow = m0 + wm + i * 16 + row16;
          const int s = grow & (S_CTX - 1);
          const float c = cosT[s * 128 + col];
          const float sn = sinT[s * 128 + col];
          const float x = fs[p * 2048 + row16 * 128 + col];
          const float xp = fs[p * 2048 + row16 * 128 + cc];
          Ch[(size_t)grow * N + n0 + col] = f2h((x * c + sgn * xp * sn) * oscale);
        }
      }
    }
    return;
  }
#pragma unroll
  for (int i = 0; i < 4; ++i)
#pragma unroll
    for (int n = 0; n < 4; ++n) {
      const int row0 = m0 + wm + i * 16 + quad * 4;
      const int col = n0 + wn + n * 16 + l16;
      if (MODE == 0) {
#pragma unroll
        for (int r = 0; r < 4; ++r) Cf[(size_t)(row0 + r) * N + col] = acc[i][n][r] * oscale;
      } else {
        int brow = row0 >> 11, s0 = row0 & 2047;
        int hh = col >> 7, d = col & 127;
        ushort4 pk;
        pk.x = f2h(acc[i][n][0]);
        pk.y = f2h(acc[i][n][1]);
        pk.z = f2h(acc[i][n][2]);
        pk.w = f2h(acc[i][n][3]);
        *(ushort4*)(Ch + ((size_t)(brow * 16 + hh) * 128 + d) * 2048 + s0) = pk;
      }
    }
}

// Fused QKV projection + RoPE: grid (16, 32, 3).
// z=0: Q (3-term, rope + qs prescale); z=1: K (3-term, rope); z=2: V (1-term, V^T out)
__global__ __launch_bounds__(256) void qkv_kernel(
    const u16* __restrict__ xh, const u16* __restrict__ xl,
    const u16* __restrict__ Wqh, const u16* __restrict__ Wql,
    const u16* __restrict__ Wkh, const u16* __restrict__ Wkl,
    const u16* __restrict__ Wvh,
    const float* __restrict__ cosT, const float* __restrict__ sinT,
    u16* qh, u16* kh, u16* vt) {
  __shared__ u16 sm[32768];  // 64 KiB: 2 x 16K u16 (NT3 dbuf) / 3 x 8K (NT1)
  const int m0 = blockIdx.y << 7, n0 = blockIdx.x << 7;
  const float qs = 0.002762135864009951f;  // sqrt(128)/4096
  if (blockIdx.z == 0)
    gemm_core<3, 3>(sm, xh, xl, Wqh, Wql, nullptr, qh, cosT, sinT, DMODEL, DMODEL, m0, n0, qs);
  else if (blockIdx.z == 1)
    gemm_core<3, 3>(sm, xh, xl, Wkh, Wkl, nullptr, kh, cosT, sinT, DMODEL, DMODEL, m0, n0, 1.f);
  else
    gemm_core<1, 2>(sm, xh, nullptr, Wvh, nullptr, nullptr, vt, nullptr, nullptr, DMODEL, DMODEL, m0, n0, 1.f);
}

// out = (ch * Woh^T) / 4096  (1-term fp16; dropped terms ~1.5e-4)
__global__ __launch_bounds__(256) void out_kernel(
    const u16* __restrict__ ch, const u16* __restrict__ Woh, float* __restrict__ out) {
  __shared__ u16 sm[24576];  // 48 KiB: 3 x 8K u16
  gemm_core<1, 0>(sm, ch, nullptr, Woh, nullptr, out, nullptr, nullptr, nullptr, DMODEL, DMODEL,
                  blockIdx.y << 7, blockIdx.x << 7, 1.f / 4096.f);
}

// Flash attention, causal. 1-term fp16 QK (q pre-scaled), f32 online softmax,
// fp16 P and PV with V^T [b][h][d][s]. BQ=128: 512 thr = 8 waves x 16 q-rows
// sharing K/V tiles (BK=64). P in its OWN per-wave LDS buffer (no aliasing,
// no barrier needed for it: strictly within-wave write->read). 2 barriers/iter.
// Register prefetch of tile kt+1.
//
// CAUSAL LOAD BALANCE (round 5): grid (8, 32); block bx processes q-tiles
// {15-bx, bx} sequentially. Work = 2(16-bx) + 2(bx+1) = 34 k-tile-steps for
// EVERY block; 256 blocks = exactly 1/CU, no tail, independent of dispatch
// mapping. (Old: 512 blocks, per-block work 2..32 steps -> heavy-CU ~2x the
// balanced load.) Per-q-tile kt order unchanged -> bit-identical output.
__global__ __launch_bounds__(512) void attn_kernel(
    const u16* __restrict__ Qh, const u16* __restrict__ Kh,
    const u16* __restrict__ VT, u16* __restrict__ Ch) {
  const int bx = blockIdx.x;  // 0..7
  const int bh = blockIdx.y;
  const int b = bh >> 4, h = bh & 15;
  const int tid = threadIdx.x;
  const int w = tid >> 6, lane = tid & 63;
  const int quad = lane >> 4, l16 = lane & 15;

  __shared__ u16 sKh[64 * 136];   // K-tile [k][d] pitch 136
  __shared__ u16 sVt[128 * 72];   // V^T tile [d][k], pitch 72
  __shared__ u16 sPb[8 * 1088];   // per-wave P, 16 x 68 each (dedicated)
  u16* sP = &sPb[w * 1088];

  const size_t bhbase = (size_t)b * S_CTX * DMODEL + (size_t)h * 128;
  const size_t vtbase = (size_t)bh * 128 * 2048;

  int kr[2], kc[2], vr[2], vc[2];
#pragma unroll
  for (int j = 0; j < 2; ++j) {
    int c = j * 512 + tid;
    kr[j] = c >> 4; kc[j] = (c & 15) << 3;
    vr[j] = c >> 3; vc[j] = (c & 7) << 3;
  }

#pragma unroll 1
  for (int pass = 0; pass < 2; ++pass) {
    const int qt = pass ? bx : 15 - bx;  // heavy q-tile first

    // Q fragments; wave w owns q-rows qt*128 + w*16 + [0,16)
    const int qr0 = qt * 128 + w * 16;
    const size_t qoff = bhbase + (size_t)(qr0 + l16) * DMODEL;
    f16x8 qf[4];
#pragma unroll
    for (int c = 0; c < 4; ++c) qf[c] = *(const f16x8*)(Qh + qoff + c * 32 + quad * 8);

    f32x4 oacc[8];
#pragma unroll
    for (int d = 0; d < 8; ++d) oacc[d] = (f32x4){0.f, 0.f, 0.f, 0.f};
    float m_r[4] = {-INFINITY, -INFINITY, -INFINITY, -INFINITY};
    float l_r[4] = {0.f, 0.f, 0.f, 0.f};

    f16x8 rkh[2], rvt[2];
#pragma unroll
    for (int j = 0; j < 2; ++j) {
      rkh[j] = *(const f16x8*)(Kh + bhbase + (size_t)kr[j] * DMODEL + kc[j]);
      rvt[j] = *(const f16x8*)(VT + vtbase + (size_t)vr[j] * 2048 + vc[j]);
    }

    const int nkt = 2 * qt + 2;
    for (int kt = 0; kt < nkt; ++kt) {
      __syncthreads();  // (1) prev iter (or prev pass) LDS reads done
#pragma unroll
      for (int j = 0; j < 2; ++j) {
        *(f16x8*)&sKh[kr[j] * 136 + kc[j]] = rkh[j];
        *(f16x8*)&sVt[vr[j] * 72 + vc[j]] = rvt[j];
      }
      __syncthreads();  // (2) tiles visible
      if (kt + 1 < nkt) {
#pragma unroll
        for (int j = 0; j < 2; ++j) {
          size_t g = bhbase + (size_t)((kt + 1) * 64 + kr[j]) * DMODEL + kc[j];
          rkh[j] = *(const f16x8*)(Kh + g);
          rvt[j] = *(const f16x8*)(VT + vtbase + (size_t)vr[j] * 2048 + (kt + 1) * 64 + vc[j]);
        }
      }

      const bool active = (kt * 64) <= (qr0 + 15);
      if (active) {
        f32x4 sacc[4];
#pragma unroll
        for (int n = 0; n < 4; ++n) sacc[n] = (f32x4){0.f, 0.f, 0.f, 0.f};
#pragma unroll
        for (int n = 0; n < 4; ++n)
#pragma unroll
          for (int c = 0; c < 4; ++c) {
            f16x8 kf = *(const f16x8*)&sKh[(n * 16 + l16) * 136 + c * 32 + quad * 8];
            sacc[n] = __builtin_amdgcn_mfma_f32_16x16x32_f16(qf[c], kf, sacc[n], 0, 0, 0);
          }

        float pm[4][4];
        float rowmax[4] = {-INFINITY, -INFINITY, -INFINITY, -INFINITY};
#pragma unroll
        for (int n = 0; n < 4; ++n)
#pragma unroll
          for (int r = 0; r < 4; ++r) {
            float sc = sacc[n][r];
            int qi = qr0 + quad * 4 + r;
            int ki = kt * 64 + n * 16 + l16;
            if (ki > qi) sc = -INFINITY;
            pm[n][r] = sc;
            rowmax[r] = fmaxf(rowmax[r], sc);
          }
#pragma unroll
        for (int off = 1; off < 16; off <<= 1)
#pragma unroll
          for (int r = 0; r < 4; ++r)
            rowmax[r] = fmaxf(rowmax[r], __shfl_xor(rowmax[r], off, 64));

        float alphav[4];
#pragma unroll
        for (int r = 0; r < 4; ++r) {
          float mnew = fmaxf(m_r[r], rowmax[r]);
          alphav[r] = __expf(m_r[r] - mnew);
          m_r[r] = mnew;
          l_r[r] *= alphav[r];
        }
        float rowsum[4] = {0.f, 0.f, 0.f, 0.f};
#pragma unroll
        for (int n = 0; n < 4; ++n)
#pragma unroll
          for (int r = 0; r < 4; ++r) {
            float p = __expf(pm[n][r] - m_r[r]);
            pm[n][r] = p;
            rowsum[r] += p;
          }
#pragma unroll
        for (int off = 1; off < 16; off <<= 1)
#pragma unroll
          for (int r = 0; r < 4; ++r) rowsum[r] += __shfl_xor(rowsum[r], off, 64);
#pragma unroll
        for (int r = 0; r < 4; ++r) l_r[r] += rowsum[r];

#pragma unroll
        for (int d = 0; d < 8; ++d)
#pragma unroll
          for (int r = 0; r < 4; ++r) oacc[d][r] *= alphav[r];

        // P (C-layout) -> per-wave dedicated LDS region -> A-layout
#pragma unroll
        for (int n = 0; n < 4; ++n)
#pragma unroll
          for (int r = 0; r < 4; ++r)
            sP[(quad * 4 + r) * 68 + n * 16 + l16] = f2h(pm[n][r]);

        // O += P.V
#pragma unroll
        for (int c = 0; c < 2; ++c) {
          f16x8 pf = *(const f16x8*)&sP[l16 * 68 + c * 32 + quad * 8];
#pragma unroll
          for (int d = 0; d < 8; ++d) {
            f16x8 vf = *(const f16x8*)&sVt[(d * 16 + l16) * 72 + c * 32 + quad * 8];
            oacc[d] = __builtin_amdgcn_mfma_f32_16x16x32_f16(pf, vf, oacc[d], 0, 0, 0);
          }
        }
      }
    }

    float invl[4];
#pragma unroll
    for (int r = 0; r < 4; ++r) invl[r] = 1.f / l_r[r];
#pragma unroll
    for (int d = 0; d < 8; ++d)
#pragma unroll
      for (int r = 0; r < 4; ++r) {
        int row = qr0 + quad * 4 + r;
        Ch[bhbase + (size_t)row * DMODEL + d * 16 + l16] = f2h(oacc[d][r] * invl[r]);
      }
  }
}

extern "C" void kernel_launch(void* const* d_in, const int* in_sizes, int n_in,
                              void* d_out, int out_size, void* d_ws, size_t ws_size,
                              hipStream_t stream) {
  const float* x    = (const float*)d_in[0];
  const float* Wq   = (const float*)d_in[1];
  const float* Wk   = (const float*)d_in[2];
  const float* Wv   = (const float*)d_in[3];
  const float* Wo   = (const float*)d_in[4];
  const float* cosT = (const float*)d_in[5];
  const float* sinT = (const float*)d_in[6];
  float* out = (float*)d_out;

  const size_t NX = 8388608;   // 2*2048*2048
  const size_t NW = 4194304;   // 2048*2048
  u16* p = (u16*)d_ws;
  u16* xh  = p; p += NX;  u16* xl  = p; p += NX;
  u16* Wqh = p; p += NW;  u16* Wql = p; p += NW;
  u16* Wkh = p; p += NW;  u16* Wkl = p; p += NW;
  u16* Wvh = p; p += NW;  u16* Woh = p; p += NW;
  u16* qh  = p; p += NX;  u16* kh  = p; p += NX;
  u16* vt  = p; p += NX;
  u16* ch  = p; p += NX;
  // ~150 MiB of d_ws

  split_all<<<98304, 256, 0, stream>>>(x, Wq, Wk, Wv, Wo,
                                       xh, xl, Wqh, Wql, Wkh, Wkl, Wvh, Woh);

  qkv_kernel<<<dim3(16, 32, 3), 256, 0, stream>>>(xh, xl, Wqh, Wql, Wkh, Wkl, Wvh,
                                                  cosT, sinT, qh, kh, vt);

  attn_kernel<<<dim3(8, 32), 512, 0, stream>>>(qh, kh, vt, ch);

  out_kernel<<<dim3(16, 32), 256, 0, stream>>>(ch, Woh, out);
}